// Round 6
// baseline (3147.353 us; speedup 1.0000x reference)
//
#include <hip/hip_runtime.h>
#include <hip/hip_bf16.h>

#define NT 1024
typedef unsigned short u16;
typedef unsigned long long u64;

__device__ __forceinline__ u16 tobf(float x) {
  union { __hip_bfloat16 h; u16 u; } cv;
  cv.h = __float2bfloat16(x);
  return cv.u;
}
__device__ __forceinline__ float frombf(u16 u) {
  return __uint_as_float(((unsigned)u) << 16);
}
__device__ __forceinline__ float sigf(float x) {
  return __builtin_amdgcn_rcpf(1.f + __builtin_amdgcn_exp2f(-1.4426950408889634f * x));
}
__device__ __forceinline__ float tanh_fast(float x) {
  return 1.f - 2.f * __builtin_amdgcn_rcpf(1.f + __builtin_amdgcn_exp2f(2.8853900817779268f * x));
}
__device__ __forceinline__ void lds_fence() {
  asm volatile("s_waitcnt lgkmcnt(0)" ::: "memory");
  __builtin_amdgcn_sched_barrier(0);
}
__device__ __forceinline__ void bar_light() {
  asm volatile("s_waitcnt lgkmcnt(0)" ::: "memory");
  __builtin_amdgcn_s_barrier();
  asm volatile("" ::: "memory");
}

// 129-tap conv, 4 consecutive outputs, sequential-k fmaf chain (bit-identical
// to the k2 form: taps ascend one at a time into each accumulator).
__device__ __forceinline__ void conv4(const u16* __restrict__ wrow,
                                      const float* __restrict__ xin,
                                      float& a0, float& a1, float& a2, float& a3) {
  float4 xc = *(const float4*)xin;
  for (int k4 = 0; k4 < 128; k4 += 4) {
    ushort4 wu = *(const ushort4*)(wrow + k4);
    float w0 = frombf(wu.x), w1 = frombf(wu.y), w2 = frombf(wu.z), w3 = frombf(wu.w);
    float4 xn = *(const float4*)(xin + k4 + 4);
    a0 = fmaf(w3, xc.w, fmaf(w2, xc.z, fmaf(w1, xc.y, fmaf(w0, xc.x, a0))));
    a1 = fmaf(w3, xn.x, fmaf(w2, xc.w, fmaf(w1, xc.z, fmaf(w0, xc.y, a1))));
    a2 = fmaf(w3, xn.y, fmaf(w2, xn.x, fmaf(w1, xc.w, fmaf(w0, xc.z, a2))));
    a3 = fmaf(w3, xn.z, fmaf(w2, xn.y, fmaf(w1, xn.x, fmaf(w0, xc.w, a3))));
    xc = xn;
  }
  float wk = frombf(wrow[128]);
  a0 = fmaf(wk, xc.x, a0); a1 = fmaf(wk, xc.y, a1);
  a2 = fmaf(wk, xc.z, a2); a3 = fmaf(wk, xc.w, a3);
}

struct SeqArgs {
  const float* input;
  const float* nv1_0; const float* nv2_0; const float* nv1_1; const float* nv2_1;
  const float* w_start0; const float* b_start0; const float* w_mlp0; const float* b_mlp0;
  const float* w_end0;   const float* b_end0;   const float* w_lin0; const float* b_lin0;
  const float* gamma0;   const float* beta0;
  const float* w_start1; const float* b_start1; const float* w_mlp1; const float* b_mlp1;
  const float* w_end1;   const float* b_end1;   const float* w_lin1; const float* b_lin1;
  const float* gamma1;   const float* beta1;
  u64*   HCOL2;  // ws ring [16][192][192] of {f32 val, u32 tag}
  int*   prog;   // ws [192*32] ints, stride 32: consumer progress (backpressure)
  float* out_all; float* out_hrow; float* out_hcol;
};

__global__ __launch_bounds__(NT, 4) void seq_kernel(SeqArgs A) {
  const int n = blockIdx.x, w = n >> 3, b = n & 7, tid = threadIdx.x;
  const int pred = (n + 184) % 192;   // n-8 mod 192
  const int succ = (n + 8) % 192;

  __shared__ __align__(16) float  sCIN[1152];    // h_row(192)|h_col(192)|xbuf0(384)|xbuf1(384)
  __shared__ __align__(16) u16    sWS[64 * 132]; // conv weights bf16, row=ich*16+c
  __shared__ __align__(16) float  sAT[4096];     // aT[w*64+v]
  __shared__ __align__(16) float  sH0[1024];     // h_t rows [c*64+v]
  __shared__ __align__(16) float  sH1[1024];     // h1 rows
  __shared__ __align__(16) float2 hI2[1024];     // {h1,h2} interleaved for G
  __shared__ __align__(16) float  sAbuf[4096];   // scores@init; sPart[0..3071]; sE@3072; stats@3456
  __shared__ __align__(16) float  sG[2048];
  __shared__ __align__(16) float  sY[1152];
  __shared__ __align__(16) float  smWE[192];
  __shared__ __align__(16) float  smBE[8];
  __shared__ __align__(16) float  smWM[32 * 52]; // stride 52: rows 16B-aligned
  float* const sPart = sAbuf;          // [0..3071] pre-conv partials (P*16*64)
  float* const sE    = sAbuf + 3072;   // [3072..3455]
  float* const smSt  = sAbuf + 3456;   // [3456..3471] LN stats (mu[6], isig@+8)

  for (int layer = 0; layer < 2; ++layer) {
    const int in_dim = 3 + layer;
    const int P = in_dim - 1;  // pre channels: h_row + x-channels
    const float* nv1    = layer ? A.nv1_1    : A.nv1_0;
    const float* nv2    = layer ? A.nv2_1    : A.nv2_0;
    const float* wstart = layer ? A.w_start1 : A.w_start0;
    const float* bs     = layer ? A.b_start1 : A.b_start0;
    const float* wm     = layer ? A.w_mlp1   : A.w_mlp0;
    const float* bm     = layer ? A.b_mlp1   : A.b_mlp0;
    const float* we     = layer ? A.w_end1   : A.w_end0;
    const float* be     = layer ? A.b_end1   : A.b_end0;
    const float* wl     = layer ? A.w_lin1   : A.w_lin0;
    const float* bl     = layer ? A.b_lin1   : A.b_lin0;
    const float* gm     = layer ? A.gamma1   : A.gamma0;
    const float* bt     = layer ? A.beta1    : A.beta0;

    // ---- layer init ----
    for (int idx = tid; idx < 4096; idx += NT) {
      int v = idx >> 6, ww = idx & 63;
      float s = 0.f;
      for (int j = 0; j < 40; ++j) s = fmaf(nv1[v*40 + j], nv2[j*64 + ww], s);
      sAbuf[idx] = fmaxf(s, 0.f);
    }
    __syncthreads();
    if (tid < 64) {
      const int v = tid;
      float m = -1e30f;
      for (int ww = 0; ww < 64; ++ww) m = fmaxf(m, sAbuf[v*64 + ww]);
      float s = 0.f;
      for (int ww = 0; ww < 64; ++ww) { float e = expf(sAbuf[v*64 + ww] - m); sAbuf[v*64 + ww] = e; s += e; }
      float inv = 1.f / s, rs = 1.f;
      for (int ww = 0; ww < 64; ++ww) rs += sAbuf[v*64 + ww] * inv;
      float irs = 1.f / rs;
      for (int ww = 0; ww < 64; ++ww) {
        float a = sAbuf[v*64 + ww] * inv + ((ww == v) ? 1.f : 0.f);
        sAT[ww*64 + v] = a * irs;
      }
    }
    __syncthreads();  // sAT ready; scores region dead
    for (int idx = tid; idx < 16*in_dim*132; idx += NT) {
      int row = idx / 132, k = idx - row*132;
      sWS[idx] = (k < 129) ? tobf(wstart[((row & 15)*in_dim + (row >> 4))*129 + k]) : (u16)0;
    }
    for (int idx = tid; idx < 1536; idx += NT) { int o = idx/48, c = idx - o*48; smWM[o*52 + c] = wm[idx]; }
    for (int idx = tid; idx < 192; idx += NT) smWE[idx] = we[idx];
    if (tid < 6) smBE[tid] = be[tid];
    for (int d = tid; d < 384; d += NT) sCIN[d] = 0.f;

    const int v_p = tid & 63;
    const int o0  = tid >> 6;         // wave id, 0..15
    const float bmv0 = bm[o0], bmv1 = bm[o0 + 16];
    const float bs_r0 = bs[o0];
    float blv = 0.f;
    if (tid < 384) blv = bl[(tid >= 192) ? tid - 192 : tid];
    // gate constants: k1 crew = tid<192 (d=tid); k2 crew = tid in [256,448) (d=tid-256)
    const int dg = (tid < 192) ? tid : ((tid >= 256 && tid < 448) ? tid - 256 : 0);
    const float gmv = gm[dg], btv = bt[dg];
    __syncthreads();

    // ---- prologue: stage x(0) -> xbuf0, conv all P channels, assemble h0pre ----
    {
      float* xb0 = &sCIN[384];
      if (layer == 0) {
        int o = 0 - w;
        for (int d = tid; d < 192; d += NT)
          xb0[d] = (o >= 0 && o < 48) ? A.input[(((size_t)(b*24 + w)*48 + o)*192) + d] : 0.f;
      } else {
        for (int d = tid; d < 384; d += NT)
          xb0[d] = A.out_all[((size_t)n*71 + 0)*384 + d];
      }
      bar_light();
      const int nps = P << 8;
      if (tid < nps) {
        int p = tid >> 8, c = (tid >> 4) & 15, v0 = (tid & 15) * 4;
        int ich = (p == 0) ? 0 : (p + 1);
        const float* xin = ((p == 0) ? &sCIN[0] : &xb0[(p-1)*192]) + v0;
        float a0 = 0.f, a1 = 0.f, a2 = 0.f, a3 = 0.f;
        conv4(&sWS[(ich*16 + c)*132], xin, a0, a1, a2, a3);
        *(float4*)&sPart[(p*16 + c)*64 + v0] = make_float4(a0, a1, a2, a3);
      }
      bar_light();
      {
        int c = tid >> 6, v = tid & 63;
        float sum = bs_r0;
        for (int p = 0; p < P; ++p) sum += sPart[(p*16 + c)*64 + v];
        sH0[c*64 + v] = sum;
      }
      bar_light();
    }

    for (int t = 0; t < 71; ++t) {
      const int S = layer*71 + t;

      // ---- poll pred's h_col (per-lane tagged, single round-trip) ----
      if (t > 0) {
        if (tid < 192) {
          const u64* src = &A.HCOL2[((size_t)((S-1) & 15)*192 + pred)*192 + tid];
          u64 v = __hip_atomic_load(src, __ATOMIC_RELAXED, __HIP_MEMORY_SCOPE_AGENT);
          while ((unsigned)(v >> 32) != (unsigned)S) {
            __builtin_amdgcn_s_sleep(1);
            v = __hip_atomic_load(src, __ATOMIC_RELAXED, __HIP_MEMORY_SCOPE_AGENT);
          }
          __builtin_amdgcn_sched_barrier(0);
          asm volatile("" ::: "memory");
          sCIN[192 + tid] = __uint_as_float((unsigned)v);
        }
        bar_light();  // Bp
        if (tid == 0)
          __hip_atomic_store(&A.prog[n*32], S, __ATOMIC_RELAXED, __HIP_MEMORY_SCOPE_AGENT);
      }

      // ---- phase A: waves 0-3 conv_hcol->prop1->prop2 (wave-local, fences);
      //      waves 8-15: x(t+1)->xbuf; tid 320: backpressure ----
      if (tid < 256) {
        const int c  = tid >> 4, v0 = (tid & 15) * 4;
        {
          float4 acc = *(const float4*)&sH0[c*64 + v0];
          float a0 = acc.x, a1 = acc.y, a2 = acc.z, a3 = acc.w;
          conv4(&sWS[(16 + c)*132], &sCIN[192 + v0], a0, a1, a2, a3);
          *(float4*)&sH0[c*64 + v0] = make_float4(a0, a1, a2, a3);
        }
        lds_fence();
        const int r0 = (tid >> 6) * 4;   // wave q rows 4q..4q+3
        float h0a[4];
#pragma unroll
        for (int j = 0; j < 4; ++j) h0a[j] = sH0[(r0+j)*64 + v_p];
        float pa[4] = {0.f, 0.f, 0.f, 0.f};
        for (int w4 = 0; w4 < 64; w4 += 4) {
          float a0v = sAT[(w4+0)*64 + v_p];
          float a1v = sAT[(w4+1)*64 + v_p];
          float a2v = sAT[(w4+2)*64 + v_p];
          float a3v = sAT[(w4+3)*64 + v_p];
#pragma unroll
          for (int j = 0; j < 4; ++j) {
            float4 hv = *(const float4*)&sH0[(r0+j)*64 + w4];
            pa[j] = fmaf(hv.x, a0v, pa[j]); pa[j] = fmaf(hv.y, a1v, pa[j]);
            pa[j] = fmaf(hv.z, a2v, pa[j]); pa[j] = fmaf(hv.w, a3v, pa[j]);
          }
        }
#pragma unroll
        for (int j = 0; j < 4; ++j) {
          float h1v = fmaf(0.95f, pa[j], 0.05f * h0a[j]);
          sH1[(r0+j)*64 + v_p] = h1v;
          hI2[(r0+j)*64 + v_p].x = h1v;
        }
        lds_fence();
        float pb[4] = {0.f, 0.f, 0.f, 0.f};
        for (int w4 = 0; w4 < 64; w4 += 4) {
          float a0v = sAT[(w4+0)*64 + v_p];
          float a1v = sAT[(w4+1)*64 + v_p];
          float a2v = sAT[(w4+2)*64 + v_p];
          float a3v = sAT[(w4+3)*64 + v_p];
#pragma unroll
          for (int j = 0; j < 4; ++j) {
            float4 hv = *(const float4*)&sH1[(r0+j)*64 + w4];
            pb[j] = fmaf(hv.x, a0v, pb[j]); pb[j] = fmaf(hv.y, a1v, pb[j]);
            pb[j] = fmaf(hv.z, a2v, pb[j]); pb[j] = fmaf(hv.w, a3v, pb[j]);
          }
        }
#pragma unroll
        for (int j = 0; j < 4; ++j)
          hI2[(r0+j)*64 + v_p].y = fmaf(0.95f, pb[j], 0.05f * h0a[j]);
      } else if (tid >= 512) {
        if (t < 70) {
          const int d = tid - 512;
          float* xbn = &sCIN[384 + ((t+1) & 1)*384];
          if (layer == 0) {
            if (d < 192) {
              int o = (t + 1) - w;
              xbn[d] = (o >= 0 && o < 48)
                     ? A.input[(((size_t)(b*24 + w)*48 + o)*192) + d] : 0.f;
            }
          } else {
            if (d < 384) xbn[d] = A.out_all[((size_t)n*71 + (t+1))*384 + d];
          }
        }
      } else if (tid == 320 && S >= 16) {
        while (__hip_atomic_load(&A.prog[succ*32], __ATOMIC_RELAXED, __HIP_MEMORY_SCOPE_AGENT) < S - 15)
          __builtin_amdgcn_s_sleep(2);
      }
      bar_light();  // B3

      // ---- G = bm + wm0 h0 + wm1 h1 + wm2 h2 ; exact GELU -> sG ----
      {
        float g0 = bmv0, g1 = bmv1;
        for (int cq = 0; cq < 4; ++cq) {
          float4 wa0 = *(const float4*)&smWM[ o0      *52      + cq*4];
          float4 wb0 = *(const float4*)&smWM[ o0      *52 + 16 + cq*4];
          float4 wc0 = *(const float4*)&smWM[ o0      *52 + 32 + cq*4];
          float4 wa1 = *(const float4*)&smWM[(o0 + 16)*52      + cq*4];
          float4 wb1 = *(const float4*)&smWM[(o0 + 16)*52 + 16 + cq*4];
          float4 wc1 = *(const float4*)&smWM[(o0 + 16)*52 + 32 + cq*4];
#pragma unroll
          for (int j = 0; j < 4; ++j) {
            int c = cq*4 + j;
            float h0v = sH0[c*64 + v_p];
            float2 hh = hI2[c*64 + v_p];
            g0 = fmaf(((const float*)&wa0)[j], h0v,
                 fmaf(((const float*)&wb0)[j], hh.x,
                 fmaf(((const float*)&wc0)[j], hh.y, g0)));
            g1 = fmaf(((const float*)&wa1)[j], h0v,
                 fmaf(((const float*)&wb1)[j], hh.x,
                 fmaf(((const float*)&wc1)[j], hh.y, g1)));
          }
        }
        g0 = 0.5f * g0 * (1.f + erff(g0 * 0.70710678118654752f));
        g1 = 0.5f * g1 * (1.f + erff(g1 * 0.70710678118654752f));
        sG[ o0      *64 + v_p] = g0;
        sG[(o0 + 16)*64 + v_p] = g1;
      }
      bar_light();  // B4

      // ---- E = be + we @ G (tid<384) ∥ conv-x(t+1) partials (tid>=512) ----
      if (tid < 384) {
        int o2 = tid >> 6, v = tid & 63;
        float acc = smBE[o2];
        for (int c4 = 0; c4 < 8; ++c4) {
          float4 wev = *(const float4*)&smWE[o2*32 + c4*4];
#pragma unroll
          for (int j = 0; j < 4; ++j)
            acc = fmaf(((const float*)&wev)[j], sG[(c4*4+j)*64 + v], acc);
        }
        sE[tid] = acc;
      } else if (tid >= 512 && t < 70) {
        int s = tid - 512;
        if (s < ((P-1) << 8)) {
          int p = 1 + (s >> 8), c = (s >> 4) & 15, v0 = (s & 15) * 4;
          const float* xin = &sCIN[384 + ((t+1) & 1)*384 + (p-1)*192 + v0];
          float a0 = 0.f, a1 = 0.f, a2 = 0.f, a3 = 0.f;
          conv4(&sWS[((p+1)*16 + c)*132], xin, a0, a1, a2, a3);
          *(float4*)&sPart[(p*16 + c)*64 + v0] = make_float4(a0, a1, a2, a3);
        }
      }
      bar_light();  // B5

      // ---- Y = bl + E @ wl^T : 384 threads, 3 rows each ----
      if (tid < 384) {
        const int d  = (tid >= 192) ? tid - 192 : tid;
        const int r0 = (tid >= 192) ? 3 : 0;
        const float4* wrow = (const float4*)(wl + d*64);
        float y0 = blv, y1 = blv, y2 = blv;
        for (int q = 0; q < 16; ++q) {
          float4 wv = wrow[q];
          float4 e0 = *(const float4*)&sE[(r0+0)*64 + q*4];
          float4 e1 = *(const float4*)&sE[(r0+1)*64 + q*4];
          float4 e2 = *(const float4*)&sE[(r0+2)*64 + q*4];
          y0 = fmaf(e0.x,wv.x, fmaf(e0.y,wv.y, fmaf(e0.z,wv.z, fmaf(e0.w,wv.w, y0))));
          y1 = fmaf(e1.x,wv.x, fmaf(e1.y,wv.y, fmaf(e1.z,wv.z, fmaf(e1.w,wv.w, y1))));
          y2 = fmaf(e2.x,wv.x, fmaf(e2.y,wv.y, fmaf(e2.z,wv.z, fmaf(e2.w,wv.w, y2))));
        }
        sY[(r0+0)*192 + d] = y0;
        sY[(r0+1)*192 + d] = y1;
        sY[(r0+2)*192 + d] = y2;
      }
      bar_light();  // B6

      // ---- LN stats -> smSt ----
      if (tid < 192) {
        const int r = tid >> 5, l32 = tid & 31;
        float sm = 0.f, sq = 0.f;
#pragma unroll
        for (int m = 0; m < 6; ++m) {
          float v = sY[r*192 + l32 + 32*m];
          sm += v; sq = fmaf(v, v, sq);
        }
#pragma unroll
        for (int off = 16; off >= 1; off >>= 1) {
          sm += __shfl_xor(sm, off);
          sq += __shfl_xor(sq, off);
        }
        if (l32 == 0) {
          float mu = sm * (1.f/192.f);
          float var = sq * (1.f/192.f) - mu*mu;
          smSt[r] = mu;
          smSt[8 + r] = rsqrtf(fmaxf(var, 0.f) + 1e-5f);
        }
      }
      bar_light();  // B7

      // ---- gates: k1 (col, tid<192) ∥ k2 (row, tid 256..447) ----
      if (tid < 192) {
        const int d = tid;
        float y2 = fmaf((sY[2*192+d] - smSt[2]) * smSt[10], gmv, btv);
        float y3 = fmaf((sY[3*192+d] - smSt[3]) * smSt[11], gmv, btv);
        float y5 = fmaf((sY[5*192+d] - smSt[5]) * smSt[13], gmv, btv);
        float ugc = sigf(y2), ogc = sigf(y3), igc = tanh_fast(y5);
        float hc = sCIN[192 + d];
        float hcn = tanh_fast(fmaf(ugc, igc, (1.f - ugc)*hc)) * ogc;
        u64 pk = ((u64)(unsigned)(S + 1) << 32) | (u64)__float_as_uint(hcn);
        __hip_atomic_store(&A.HCOL2[((size_t)(S & 15)*192 + n)*192 + d], pk,
                           __ATOMIC_RELAXED, __HIP_MEMORY_SCOPE_AGENT);
        float* oa = A.out_all + ((size_t)n*71 + t)*384;
        oa[192 + d] = layer ? (hcn + sCIN[384 + (t & 1)*384 + 192 + d]) : hcn;
        if (w == 23 && t >= 23)
          A.out_hcol[(((size_t)b*2 + layer)*48 + (t - 23))*192 + d] = hcn;
      } else if (tid >= 256 && tid < 448) {
        const int d = tid - 256;
        float y0 = fmaf((sY[0*192+d] - smSt[0]) * smSt[8],  gmv, btv);
        float y1 = fmaf((sY[1*192+d] - smSt[1]) * smSt[9],  gmv, btv);
        float y4 = fmaf((sY[4*192+d] - smSt[4]) * smSt[12], gmv, btv);
        float ugr = sigf(y0), ogr = sigf(y1), igr = tanh_fast(y4);
        float hr = sCIN[d];
        float hrn = tanh_fast(fmaf(ugr, igr, (1.f - ugr)*hr)) * ogr;
        sCIN[d] = hrn;
        float* oa = A.out_all + ((size_t)n*71 + t)*384;
        oa[d] = layer ? (hrn + sCIN[384 + (t & 1)*384 + d]) : hrn;
        if (t == 47 + w)
          A.out_hrow[(((size_t)b*2 + layer)*24 + w)*192 + d] = hrn;
      }
      bar_light();  // B9

      // ---- tail: conv_hrow(t+1) partials + assemble h0pre(t+1) ----
      if (t < 70) {
        if (tid < 256) {
          int c = tid >> 4, v0 = (tid & 15) * 4;
          float a0 = 0.f, a1 = 0.f, a2 = 0.f, a3 = 0.f;
          conv4(&sWS[c*132], &sCIN[v0], a0, a1, a2, a3);
          *(float4*)&sPart[c*64 + v0] = make_float4(a0, a1, a2, a3);
        }
        bar_light();  // B10
        {
          int c = tid >> 6, v = tid & 63;
          float sum = bs_r0;
          for (int p = 0; p < P; ++p) sum += sPart[(p*16 + c)*64 + v];
          sH0[c*64 + v] = sum;
        }
        bar_light();  // B11
      }
    } // t
    __syncthreads();  // drain out_all before next layer reads it
  } // layer
}

extern "C" void kernel_launch(void* const* d_in, const int* in_sizes, int n_in,
                              void* d_out, int out_size, void* d_ws, size_t ws_size,
                              hipStream_t stream) {
  (void)in_sizes; (void)n_in; (void)out_size; (void)ws_size;
  char* ws = (char*)d_ws;
  int* prog  = (int*)ws;                   // 24,576 B (192 x 128B)
  u64* HCOL2 = (u64*)(ws + 24576);         // 16*192*192*8 = 4,718,592 B

  (void)hipMemsetAsync(ws, 0, 24576 + 4718592, stream);  // zero prog + tags

  SeqArgs A;
  A.input    = (const float*)d_in[0];
  A.nv1_0    = (const float*)d_in[1];  A.nv2_0 = (const float*)d_in[2];
  A.w_start0 = (const float*)d_in[3];  A.b_start0 = (const float*)d_in[4];
  A.w_mlp0   = (const float*)d_in[5];  A.b_mlp0   = (const float*)d_in[6];
  A.w_end0   = (const float*)d_in[7];  A.b_end0   = (const float*)d_in[8];
  A.w_lin0   = (const float*)d_in[9];  A.b_lin0   = (const float*)d_in[10];
  A.gamma0   = (const float*)d_in[11]; A.beta0    = (const float*)d_in[12];
  A.nv1_1    = (const float*)d_in[13]; A.nv2_1 = (const float*)d_in[14];
  A.w_start1 = (const float*)d_in[15]; A.b_start1 = (const float*)d_in[16];
  A.w_mlp1   = (const float*)d_in[17]; A.b_mlp1   = (const float*)d_in[18];
  A.w_end1   = (const float*)d_in[19]; A.b_end1   = (const float*)d_in[20];
  A.w_lin1   = (const float*)d_in[21]; A.b_lin1   = (const float*)d_in[22];
  A.gamma1   = (const float*)d_in[23]; A.beta1    = (const float*)d_in[24];
  A.HCOL2 = HCOL2; A.prog = prog;
  A.out_all  = (float*)d_out;
  A.out_hrow = (float*)d_out + 5234688;
  A.out_hcol = (float*)d_out + 5308416;

  seq_kernel<<<192, NT, 0, stream>>>(A);
}

// Round 7
// 2715.075 us; speedup vs baseline: 1.1592x; 1.1592x over previous
//
#include <hip/hip_runtime.h>
#include <hip/hip_bf16.h>

#define NT 512
typedef unsigned short u16;
typedef unsigned long long u64;

__device__ __forceinline__ u16 tobf(float x) {
  union { __hip_bfloat16 h; u16 u; } cv;
  cv.h = __float2bfloat16(x);
  return cv.u;
}
__device__ __forceinline__ float frombf(u16 u) {
  return __uint_as_float(((unsigned)u) << 16);
}
__device__ __forceinline__ float sigf(float x) {
  return __builtin_amdgcn_rcpf(1.f + __builtin_amdgcn_exp2f(-1.4426950408889634f * x));
}
__device__ __forceinline__ float tanh_fast(float x) {
  return 1.f - 2.f * __builtin_amdgcn_rcpf(1.f + __builtin_amdgcn_exp2f(2.8853900817779268f * x));
}
__device__ __forceinline__ void lds_fence() {
  asm volatile("s_waitcnt lgkmcnt(0)" ::: "memory");
  __builtin_amdgcn_sched_barrier(0);
}
__device__ __forceinline__ void bar_light() {
  asm volatile("s_waitcnt lgkmcnt(0)" ::: "memory");
  __builtin_amdgcn_s_barrier();
  asm volatile("" ::: "memory");
}

struct SeqArgs {
  const float* input;
  const float* nv1_0; const float* nv2_0; const float* nv1_1; const float* nv2_1;
  const float* w_start0; const float* b_start0; const float* w_mlp0; const float* b_mlp0;
  const float* w_end0;   const float* b_end0;   const float* w_lin0; const float* b_lin0;
  const float* gamma0;   const float* beta0;
  const float* w_start1; const float* b_start1; const float* w_mlp1; const float* b_mlp1;
  const float* w_end1;   const float* b_end1;   const float* w_lin1; const float* b_lin1;
  const float* gamma1;   const float* beta1;
  u64*   HCOL2;  // ws ring [16][192][192] of {f32 val, u32 tag}
  int*   prog;   // ws [192*32] ints, stride 32: consumer progress (backpressure)
  float* out_all; float* out_hrow; float* out_hcol;
};

__global__ __launch_bounds__(NT, 2) void seq_kernel(SeqArgs A) {
  const int n = blockIdx.x, w = n >> 3, b = n & 7, tid = threadIdx.x;
  const int pred = (n + 184) % 192;   // n-8 mod 192
  const int succ = (n + 8) % 192;

  __shared__ __align__(16) float sCIN[768];     // [h_row(192) | unused(192) | x(384)]
  __shared__ __align__(16) float sWSf[64 * 132];// conv weights fp32 (bf16-rounded)
  __shared__ __align__(16) float sAT[4096];     // aT[w*64+v]
  __shared__ __align__(16) float sH[2][1024];   // h0 / h1 rows [c*64+v]
  __shared__ __align__(16) float sAbuf[4928];
  __shared__ __align__(16) float sHCbuf[2][192];// h_col double buffer
  __shared__ int sPreOK;
  float* const sPart = sAbuf;          // [0..3071] pre-conv partials (P*16*64)
  float* const sG    = sAbuf;          // [0..2047]
  float* const sH2c  = sAbuf + 2048;   // [2048..3071] h2 rows (dead after G)
  float* const sE    = sAbuf + 2048;   // [2048..2431] (overwrites dead h2)
  float* const sY    = sAbuf;          // [0..1151]   (overwrites dead sG)
  float* const smWE  = sAbuf + 3072;   // 192
  float* const smBE  = sAbuf + 3264;   // 6
  float* const smWM  = sAbuf + 3328;   // 32*50 (stride 50: bank-conflict-free)

  for (int layer = 0; layer < 2; ++layer) {
    const int in_dim = 3 + layer;
    const int P = in_dim - 1;  // pre channels: h_row + x-channels
    const float* nv1    = layer ? A.nv1_1    : A.nv1_0;
    const float* nv2    = layer ? A.nv2_1    : A.nv2_0;
    const float* wstart = layer ? A.w_start1 : A.w_start0;
    const float* bs     = layer ? A.b_start1 : A.b_start0;
    const float* wm     = layer ? A.w_mlp1   : A.w_mlp0;
    const float* bm     = layer ? A.b_mlp1   : A.b_mlp0;
    const float* we     = layer ? A.w_end1   : A.w_end0;
    const float* be     = layer ? A.b_end1   : A.b_end0;
    const float* wl     = layer ? A.w_lin1   : A.w_lin0;
    const float* bl     = layer ? A.b_lin1   : A.b_lin0;
    const float* gm     = layer ? A.gamma1   : A.gamma0;
    const float* bt     = layer ? A.beta1    : A.beta0;

    // ---- layer init: adjacency, weights (fp32, bf16-rounded), state zero ----
    for (int idx = tid; idx < 4096; idx += NT) {
      int v = idx >> 6, ww = idx & 63;
      float s = 0.f;
      for (int j = 0; j < 40; ++j) s = fmaf(nv1[v*40 + j], nv2[j*64 + ww], s);
      sAbuf[idx] = fmaxf(s, 0.f);
    }
    __syncthreads();
    if (tid < 64) {
      const int v = tid;
      float m = -1e30f;
      for (int ww = 0; ww < 64; ++ww) m = fmaxf(m, sAbuf[v*64 + ww]);
      float s = 0.f;
      for (int ww = 0; ww < 64; ++ww) { float e = expf(sAbuf[v*64 + ww] - m); sAbuf[v*64 + ww] = e; s += e; }
      float inv = 1.f / s, rs = 1.f;
      for (int ww = 0; ww < 64; ++ww) rs += sAbuf[v*64 + ww] * inv;
      float irs = 1.f / rs;
      for (int ww = 0; ww < 64; ++ww) {
        float a = sAbuf[v*64 + ww] * inv + ((ww == v) ? 1.f : 0.f);
        sAT[ww*64 + v] = a * irs;
      }
    }
    __syncthreads();  // sAT ready; scores region dead
    for (int idx = tid; idx < 16*in_dim*132; idx += NT) {
      int row = idx / 132, k = idx - row*132;
      sWSf[idx] = (k < 129) ? frombf(tobf(wstart[((row & 15)*in_dim + (row >> 4))*129 + k])) : 0.f;
    }
    for (int idx = tid; idx < 1536; idx += NT) { int o = idx/48, c = idx - o*48; smWM[o*50 + c] = wm[idx]; }
    for (int idx = tid; idx < 192; idx += NT) smWE[idx] = we[idx];
    if (tid < 6) smBE[tid] = be[tid];
    for (int d = tid; d < 192; d += NT) sCIN[d] = 0.f;
    for (int d = tid; d < 384; d += NT) ((float*)sHCbuf)[d] = 0.f;
    if (tid == 0) sPreOK = 0;

    const int v_p = tid & 63;
    const int o0  = tid >> 6;         // wave id, 0..7
    const float bmv0 = bm[o0], bmv1 = bm[o0 + 8], bmv2 = bm[o0 + 16], bmv3 = bm[o0 + 24];
    float blv = 0.f, gmv = 1.f, btv = 0.f;
    if (tid < 384) blv = bl[(tid >= 192) ? tid - 192 : tid];
    if (tid < 192) { gmv = gm[tid]; btv = bt[tid]; }
    float bs_r[2];
    bs_r[0] = bs[tid >> 6];
    bs_r[1] = bs[(tid >> 6) + 8];
    __syncthreads();

    // ---- conv+assemble of pre channels (x must already be in sCIN[384..]) ----
    auto pre_conv = [&]() {
      const int nslots = P << 8;
      for (int s = tid; s < nslots; s += NT) {
        const int cidx = s >> 4;
        const int p = cidx >> 4, c = cidx & 15;
        const int vg = s & 15;
        const int ich = (p == 0) ? 0 : (p + 1);
        const float* xin = ((p == 0) ? &sCIN[0] : &sCIN[384 + (p-1)*192]) + vg*4;
        const float* wrow = &sWSf[(ich*16 + c)*132];
        float a0 = 0.f, a1 = 0.f, a2 = 0.f, a3 = 0.f;
        float4 xc = *(const float4*)xin;
        for (int k4 = 0; k4 < 128; k4 += 4) {
          float4 wv = *(const float4*)(wrow + k4);
          float4 xn = *(const float4*)(xin + k4 + 4);
          a0 = fmaf(wv.w, xc.w, fmaf(wv.z, xc.z, fmaf(wv.y, xc.y, fmaf(wv.x, xc.x, a0))));
          a1 = fmaf(wv.w, xn.x, fmaf(wv.z, xc.w, fmaf(wv.y, xc.z, fmaf(wv.x, xc.y, a1))));
          a2 = fmaf(wv.w, xn.y, fmaf(wv.z, xn.x, fmaf(wv.y, xc.w, fmaf(wv.x, xc.z, a2))));
          a3 = fmaf(wv.w, xn.z, fmaf(wv.z, xn.y, fmaf(wv.y, xn.x, fmaf(wv.x, xc.w, a3))));
          xc = xn;
        }
        float wk = wrow[128];
        a0 = fmaf(wk, xc.x, a0); a1 = fmaf(wk, xc.y, a1);
        a2 = fmaf(wk, xc.z, a2); a3 = fmaf(wk, xc.w, a3);
        *(float4*)&sPart[cidx*64 + vg*4] = make_float4(a0, a1, a2, a3);
      }
      bar_light();
      {
        const int c0 = tid >> 6, v = tid & 63;
        float sum0 = bs_r[0], sum1 = bs_r[1];
        for (int p = 0; p < P; ++p) {
          sum0 += sPart[(p*16 + c0     )*64 + v];
          sum1 += sPart[(p*16 + c0 + 8 )*64 + v];
        }
        sH[0][ c0      *64 + v] = sum0;
        sH[0][(c0 + 8 )*64 + v] = sum1;
      }
      bar_light();
    };

    // ---- t=0 staging: x(0) direct from global ----
    {
      if (layer == 0) {
        int o = 0 - w;
        if (o >= 0 && o < 48) {
          const float* xr = A.input + (((size_t)(b*24 + w)*48 + o)*192);
          for (int d = tid; d < 192; d += NT) sCIN[384 + d] = xr[d];
        } else {
          for (int d = tid; d < 192; d += NT) sCIN[384 + d] = 0.f;
        }
      } else {
        const float* xr = A.out_all + ((size_t)n*71 + 0)*384;
        for (int d = tid; d < 384; d += NT) sCIN[384 + d] = xr[d];
      }
      bar_light();
      pre_conv();
    }

    for (int t = 0; t < 71; ++t) {
      const int S = layer*71 + t;

      // ---- x(t+1) prefetch into registers (latency overlaps whole step) ----
      float xpa = 0.f, xpb = 0.f;
      if (t < 70 && tid < 192) {
        if (layer == 0) {
          int o = (t + 1) - w;
          if (o >= 0 && o < 48)
            xpa = A.input[(((size_t)(b*24 + w)*48 + o)*192) + tid];
        } else {
          const float* xr = A.out_all + ((size_t)n*71 + (t+1))*384;
          xpa = xr[tid];
          xpb = xr[192 + tid];
        }
      }

      // ---- dependent path: prefetched h_col, or fallback per-lane tagged poll ----
      if (t > 0) {
        const int pok = sPreOK;
        if (tid < 192) {
          if (!pok) {
            const u64* src = &A.HCOL2[((size_t)((S-1) & 15)*192 + pred)*192 + tid];
            u64 v = __hip_atomic_load(src, __ATOMIC_RELAXED, __HIP_MEMORY_SCOPE_AGENT);
            while ((unsigned)(v >> 32) != (unsigned)S) {
              __builtin_amdgcn_s_sleep(1);
              v = __hip_atomic_load(src, __ATOMIC_RELAXED, __HIP_MEMORY_SCOPE_AGENT);
            }
            __builtin_amdgcn_sched_barrier(0);
            asm volatile("" ::: "memory");
            sHCbuf[t & 1][tid] = __uint_as_float((unsigned)v);
          }
        } else if (tid == 256 && S >= 16) {
          // backpressure: slot S&15 holds step S-16; its consumer posted prog>=S-15
          while (__hip_atomic_load(&A.prog[succ*32], __ATOMIC_RELAXED, __HIP_MEMORY_SCOPE_AGENT) < S - 15)
            __builtin_amdgcn_s_sleep(2);
        }
        bar_light();  // Bp
        if (tid == 0) {
          sPreOK = 0;
          __hip_atomic_store(&A.prog[n*32], S, __ATOMIC_RELAXED, __HIP_MEMORY_SCOPE_AGENT);
        }
      } else if (S >= 16) {  // t==0, layer 1: still must respect ring reuse
        if (tid == 256) {
          while (__hip_atomic_load(&A.prog[succ*32], __ATOMIC_RELAXED, __HIP_MEMORY_SCOPE_AGENT) < S - 15)
            __builtin_amdgcn_s_sleep(2);
        }
        if (tid == 0) sPreOK = 0;
      }

      // ---- phase A (wave-local, no block barriers): h_col conv -> prop1 -> prop2
      {
        const int c = tid >> 5, vg2 = tid & 31;
        const int vbase = c*64 + vg2*2;
        const float* xin = &sHCbuf[t & 1][vg2*2];
        const float* wrow = &sWSf[(16 + c)*132];
        float a0 = sH[0][vbase], a1 = sH[0][vbase + 1];
        float2 xc = *(const float2*)xin;
        for (int k2 = 0; k2 < 128; k2 += 2) {
          float2 wv = *(const float2*)(wrow + k2);
          float2 xn = *(const float2*)(xin + k2 + 2);
          a0 = fmaf(wv.y, xc.y, fmaf(wv.x, xc.x, a0));
          a1 = fmaf(wv.y, xn.x, fmaf(wv.x, xc.y, a1));
          xc = xn;
        }
        float wk = wrow[128];
        a0 = fmaf(wk, xc.x, a0); a1 = fmaf(wk, xc.y, a1);
        sH[0][vbase] = a0; sH[0][vbase + 1] = a1;
      }
      lds_fence();
      {
        const int c0 = o0 * 2;   // this wave's 2 rows
        float pa0 = 0.f, pa1 = 0.f;
        for (int w4 = 0; w4 < 64; w4 += 4) {
          float a0v = sAT[(w4+0)*64 + v_p];
          float a1v = sAT[(w4+1)*64 + v_p];
          float a2v = sAT[(w4+2)*64 + v_p];
          float a3v = sAT[(w4+3)*64 + v_p];
          float4 h0v = *(const float4*)&sH[0][ c0      *64 + w4];
          float4 h1v = *(const float4*)&sH[0][(c0 + 1 )*64 + w4];
          pa0 = fmaf(h0v.x, a0v, pa0); pa0 = fmaf(h0v.y, a1v, pa0);
          pa0 = fmaf(h0v.z, a2v, pa0); pa0 = fmaf(h0v.w, a3v, pa0);
          pa1 = fmaf(h1v.x, a0v, pa1); pa1 = fmaf(h1v.y, a1v, pa1);
          pa1 = fmaf(h1v.z, a2v, pa1); pa1 = fmaf(h1v.w, a3v, pa1);
        }
        float h0a = sH[0][ c0      *64 + v_p];
        float h0b = sH[0][(c0 + 1 )*64 + v_p];
        sH[1][ c0      *64 + v_p] = fmaf(0.95f, pa0, 0.05f * h0a);
        sH[1][(c0 + 1 )*64 + v_p] = fmaf(0.95f, pa1, 0.05f * h0b);
        lds_fence();
        float pb0 = 0.f, pb1 = 0.f;
        for (int w4 = 0; w4 < 64; w4 += 4) {
          float a0v = sAT[(w4+0)*64 + v_p];
          float a1v = sAT[(w4+1)*64 + v_p];
          float a2v = sAT[(w4+2)*64 + v_p];
          float a3v = sAT[(w4+3)*64 + v_p];
          float4 h0v = *(const float4*)&sH[1][ c0      *64 + w4];
          float4 h1v = *(const float4*)&sH[1][(c0 + 1 )*64 + w4];
          pb0 = fmaf(h0v.x, a0v, pb0); pb0 = fmaf(h0v.y, a1v, pb0);
          pb0 = fmaf(h0v.z, a2v, pb0); pb0 = fmaf(h0v.w, a3v, pb0);
          pb1 = fmaf(h1v.x, a0v, pb1); pb1 = fmaf(h1v.y, a1v, pb1);
          pb1 = fmaf(h1v.z, a2v, pb1); pb1 = fmaf(h1v.w, a3v, pb1);
        }
        sH2c[ c0      *64 + v_p] = fmaf(0.95f, pb0, 0.05f * h0a);
        sH2c[(c0 + 1 )*64 + v_p] = fmaf(0.95f, pb1, 0.05f * h0b);
      }
      bar_light();  // B3: h0/h1/h2 all ready

      // (g) G = bm + wm0 h0 + wm1 h1 + wm2 h2; exact GELU -> sG
      {
        float g0 = bmv0, g1 = bmv1, g2 = bmv2, g3 = bmv3;
#pragma unroll
        for (int c = 0; c < 16; ++c) {
          float h0v = sH[0][c*64 + v_p];
          float h1v = sH[1][c*64 + v_p];
          float h2v = sH2c[c*64 + v_p];
          g0 = fmaf(smWM[(o0     )*50 + c], h0v, fmaf(smWM[(o0     )*50 + 16 + c], h1v, fmaf(smWM[(o0     )*50 + 32 + c], h2v, g0)));
          g1 = fmaf(smWM[(o0 +  8)*50 + c], h0v, fmaf(smWM[(o0 +  8)*50 + 16 + c], h1v, fmaf(smWM[(o0 +  8)*50 + 32 + c], h2v, g1)));
          g2 = fmaf(smWM[(o0 + 16)*50 + c], h0v, fmaf(smWM[(o0 + 16)*50 + 16 + c], h1v, fmaf(smWM[(o0 + 16)*50 + 32 + c], h2v, g2)));
          g3 = fmaf(smWM[(o0 + 24)*50 + c], h0v, fmaf(smWM[(o0 + 24)*50 + 16 + c], h1v, fmaf(smWM[(o0 + 24)*50 + 32 + c], h2v, g3)));
        }
        g0 = 0.5f * g0 * (1.f + erff(g0 * 0.70710678118654752f));
        g1 = 0.5f * g1 * (1.f + erff(g1 * 0.70710678118654752f));
        g2 = 0.5f * g2 * (1.f + erff(g2 * 0.70710678118654752f));
        g3 = 0.5f * g3 * (1.f + erff(g3 * 0.70710678118654752f));
        sG[(o0     )*64 + v_p] = g0;
        sG[(o0 +  8)*64 + v_p] = g1;
        sG[(o0 + 16)*64 + v_p] = g2;
        sG[(o0 + 24)*64 + v_p] = g3;
      }
      bar_light();  // B4 (h2 region now dead -> sE may overwrite)

      // (h) E = be + we @ G
      for (int idx = tid; idx < 384; idx += NT) {
        int o2 = idx >> 6, v = idx & 63;
        float acc = smBE[o2];
        for (int c = 0; c < 32; ++c) acc = fmaf(smWE[o2*32 + c], sG[c*64 + v], acc);
        sE[idx] = acc;
      }
      bar_light();  // B5

      // (i) Y = bl + E @ wl^T : 384 threads, 3 rows each
      if (tid < 384) {
        const int d  = (tid >= 192) ? tid - 192 : tid;
        const int r0 = (tid >= 192) ? 3 : 0;
        const float4* wrow = (const float4*)(wl + d*64);
        float y0 = blv, y1 = blv, y2 = blv;
        for (int q = 0; q < 16; ++q) {
          float4 wv = wrow[q];
          float4 e0 = *(const float4*)&sE[(r0+0)*64 + q*4];
          float4 e1 = *(const float4*)&sE[(r0+1)*64 + q*4];
          float4 e2 = *(const float4*)&sE[(r0+2)*64 + q*4];
          y0 = fmaf(e0.x,wv.x, fmaf(e0.y,wv.y, fmaf(e0.z,wv.z, fmaf(e0.w,wv.w, y0))));
          y1 = fmaf(e1.x,wv.x, fmaf(e1.y,wv.y, fmaf(e1.z,wv.z, fmaf(e1.w,wv.w, y1))));
          y2 = fmaf(e2.x,wv.x, fmaf(e2.y,wv.y, fmaf(e2.z,wv.z, fmaf(e2.w,wv.w, y2))));
        }
        sY[(r0+0)*192 + d] = y0;
        sY[(r0+1)*192 + d] = y1;
        sY[(r0+2)*192 + d] = y2;
      }
      bar_light();  // B6

      // (j1) LN stats -> sH[1][0..13]
      if (tid < 192) {
        const int r = tid >> 5, l32 = tid & 31;
        float sm = 0.f, sq = 0.f;
#pragma unroll
        for (int m = 0; m < 6; ++m) {
          float v = sY[r*192 + l32 + 32*m];
          sm += v; sq = fmaf(v, v, sq);
        }
#pragma unroll
        for (int off = 16; off >= 1; off >>= 1) {
          sm += __shfl_xor(sm, off);
          sq += __shfl_xor(sq, off);
        }
        if (l32 == 0) {
          float mu = sm * (1.f/192.f);
          float var = sq * (1.f/192.f) - mu*mu;
          sH[1][r] = mu;
          sH[1][8 + r] = rsqrtf(fmaxf(var, 0.f) + 1e-5f);
        }
      }
      bar_light();  // B7

      float hcn = 0.f;
      // (k1) col gates -> hcn -> tagged 8B store; (prefetch crew: wave 7)
      if (tid < 192) {
        const int d = tid;
        float y2 = fmaf((sY[2*192+d] - sH[1][2]) * sH[1][10], gmv, btv);
        float y3 = fmaf((sY[3*192+d] - sH[1][3]) * sH[1][11], gmv, btv);
        float y5 = fmaf((sY[5*192+d] - sH[1][5]) * sH[1][13], gmv, btv);
        float ugc = sigf(y2), ogc = sigf(y3), igc = tanh_fast(y5);
        float hc = sHCbuf[t & 1][d];
        hcn = tanh_fast(fmaf(ugc, igc, (1.f - ugc)*hc)) * ogc;
        u64 pk = ((u64)(unsigned)(S + 1) << 32) | (u64)__float_as_uint(hcn);
        __hip_atomic_store(&A.HCOL2[((size_t)(S & 15)*192 + n)*192 + d], pk,
                           __ATOMIC_RELAXED, __HIP_MEMORY_SCOPE_AGENT);
      } else if (tid >= 448 && t < 70) {
        // wave 7: prefetch next step's h_col (bounded spin; safe fallback)
        const int l = tid - 448;                 // 0..63, one full wave
        const unsigned Sn = (unsigned)(S + 1);
        const u64* base = &A.HCOL2[((size_t)(S & 15)*192 + pred)*192];
        bool ok = true;
        u64 v0, v1, v2;
        {
          const u64* src = base + l;
          v0 = __hip_atomic_load(src, __ATOMIC_RELAXED, __HIP_MEMORY_SCOPE_AGENT);
          for (int sp = 0; sp < 16 && (unsigned)(v0 >> 32) != Sn; ++sp) {
            __builtin_amdgcn_s_sleep(1);
            v0 = __hip_atomic_load(src, __ATOMIC_RELAXED, __HIP_MEMORY_SCOPE_AGENT);
          }
          ok &= ((unsigned)(v0 >> 32) == Sn);
        }
        {
          const u64* src = base + l + 64;
          v1 = __hip_atomic_load(src, __ATOMIC_RELAXED, __HIP_MEMORY_SCOPE_AGENT);
          for (int sp = 0; sp < 16 && (unsigned)(v1 >> 32) != Sn; ++sp) {
            __builtin_amdgcn_s_sleep(1);
            v1 = __hip_atomic_load(src, __ATOMIC_RELAXED, __HIP_MEMORY_SCOPE_AGENT);
          }
          ok &= ((unsigned)(v1 >> 32) == Sn);
        }
        {
          const u64* src = base + l + 128;
          v2 = __hip_atomic_load(src, __ATOMIC_RELAXED, __HIP_MEMORY_SCOPE_AGENT);
          for (int sp = 0; sp < 16 && (unsigned)(v2 >> 32) != Sn; ++sp) {
            __builtin_amdgcn_s_sleep(1);
            v2 = __hip_atomic_load(src, __ATOMIC_RELAXED, __HIP_MEMORY_SCOPE_AGENT);
          }
          ok &= ((unsigned)(v2 >> 32) == Sn);
        }
        float* dstb = &sHCbuf[(t + 1) & 1][0];
        dstb[l]       = __uint_as_float((unsigned)v0);
        dstb[l + 64]  = __uint_as_float((unsigned)v1);
        dstb[l + 128] = __uint_as_float((unsigned)v2);
        u64 bal = __ballot(ok);
        if (l == 0) sPreOK = (bal == ~0ull) ? 1 : 0;
      }
      // (k2) row gates + outputs + x(t+1) publish (off critical path)
      if (tid < 192) {
        const int d = tid;
        float y0 = fmaf((sY[0*192+d] - sH[1][0]) * sH[1][8],  gmv, btv);
        float y1 = fmaf((sY[1*192+d] - sH[1][1]) * sH[1][9],  gmv, btv);
        float y4 = fmaf((sY[4*192+d] - sH[1][4]) * sH[1][12], gmv, btv);
        float ugr = sigf(y0), ogr = sigf(y1), igr = tanh_fast(y4);
        float hr = sCIN[d];
        float hrn = tanh_fast(fmaf(ugr, igr, (1.f - ugr)*hr)) * ogr;
        sCIN[d] = hrn;
        float* oa = A.out_all + ((size_t)n*71 + t)*384;
        if (layer == 0) { oa[d] = hrn; oa[192 + d] = hcn; }
        else           { oa[d] = hrn + sCIN[384 + d]; oa[192 + d] = hcn + sCIN[576 + d]; }
        if (t == 47 + w)
          A.out_hrow[(((size_t)b*2 + layer)*24 + w)*192 + d] = hrn;
        if (w == 23 && t >= 23)
          A.out_hcol[(((size_t)b*2 + layer)*48 + (t - 23))*192 + d] = hcn;
        // publish prefetched x(t+1) (same threads that read x(t) above: no hazard)
        if (t < 70) {
          sCIN[384 + d] = xpa;
          if (layer == 1) sCIN[576 + d] = xpb;
        }
      }
      bar_light();  // B9: h_row + x(t+1) + prefetched h_col visible
      if (t < 70) pre_conv();
    } // t
    __syncthreads();  // full barrier: drain out_all stores before next layer reads
  } // layer
}

extern "C" void kernel_launch(void* const* d_in, const int* in_sizes, int n_in,
                              void* d_out, int out_size, void* d_ws, size_t ws_size,
                              hipStream_t stream) {
  (void)in_sizes; (void)n_in; (void)out_size; (void)ws_size;
  char* ws = (char*)d_ws;
  int* prog  = (int*)ws;                   // 24,576 B (192 x 128B)
  u64* HCOL2 = (u64*)(ws + 24576);         // 16*192*192*8 = 4,718,592 B

  (void)hipMemsetAsync(ws, 0, 24576 + 4718592, stream);  // zero prog + tags

  SeqArgs A;
  A.input    = (const float*)d_in[0];
  A.nv1_0    = (const float*)d_in[1];  A.nv2_0 = (const float*)d_in[2];
  A.w_start0 = (const float*)d_in[3];  A.b_start0 = (const float*)d_in[4];
  A.w_mlp0   = (const float*)d_in[5];  A.b_mlp0   = (const float*)d_in[6];
  A.w_end0   = (const float*)d_in[7];  A.b_end0   = (const float*)d_in[8];
  A.w_lin0   = (const float*)d_in[9];  A.b_lin0   = (const float*)d_in[10];
  A.gamma0   = (const float*)d_in[11]; A.beta0    = (const float*)d_in[12];
  A.nv1_1    = (const float*)d_in[13]; A.nv2_1 = (const float*)d_in[14];
  A.w_start1 = (const float*)d_in[15]; A.b_start1 = (const float*)d_in[16];
  A.w_mlp1   = (const float*)d_in[17]; A.b_mlp1   = (const float*)d_in[18];
  A.w_end1   = (const float*)d_in[19]; A.b_end1   = (const float*)d_in[20];
  A.w_lin1   = (const float*)d_in[21]; A.b_lin1   = (const float*)d_in[22];
  A.gamma1   = (const float*)d_in[23]; A.beta1    = (const float*)d_in[24];
  A.HCOL2 = HCOL2; A.prog = prog;
  A.out_all  = (float*)d_out;
  A.out_hrow = (float*)d_out + 5234688;
  A.out_hcol = (float*)d_out + 5308416;

  seq_kernel<<<192, NT, 0, stream>>>(A);
}

// Round 8
// 2671.572 us; speedup vs baseline: 1.1781x; 1.0163x over previous
//
#include <hip/hip_runtime.h>
#include <hip/hip_bf16.h>

#define NT 512
typedef unsigned short u16;
typedef unsigned long long u64;

__device__ __forceinline__ u16 tobf(float x) {
  union { __hip_bfloat16 h; u16 u; } cv;
  cv.h = __float2bfloat16(x);
  return cv.u;
}
__device__ __forceinline__ float frombf(u16 u) {
  return __uint_as_float(((unsigned)u) << 16);
}
__device__ __forceinline__ float sigf(float x) {
  return __builtin_amdgcn_rcpf(1.f + __builtin_amdgcn_exp2f(-1.4426950408889634f * x));
}
__device__ __forceinline__ float tanh_fast(float x) {
  return 1.f - 2.f * __builtin_amdgcn_rcpf(1.f + __builtin_amdgcn_exp2f(2.8853900817779268f * x));
}
__device__ __forceinline__ void lds_fence() {
  asm volatile("s_waitcnt lgkmcnt(0)" ::: "memory");
  __builtin_amdgcn_sched_barrier(0);
}
__device__ __forceinline__ void bar_light() {
  asm volatile("s_waitcnt lgkmcnt(0)" ::: "memory");
  __builtin_amdgcn_s_barrier();
  asm volatile("" ::: "memory");
}

// 129-tap conv, 4 consecutive outputs, fp32 (bf16-rounded) weights.
// Tap order ascending per accumulator: bit-identical to reference chain.
__device__ __forceinline__ void conv4(const float* __restrict__ wrow,
                                      const float* __restrict__ xin,
                                      float& a0, float& a1, float& a2, float& a3) {
  float4 xc = *(const float4*)xin;
  for (int k4 = 0; k4 < 128; k4 += 4) {
    float4 wv = *(const float4*)(wrow + k4);
    float4 xn = *(const float4*)(xin + k4 + 4);
    a0 = fmaf(wv.w, xc.w, fmaf(wv.z, xc.z, fmaf(wv.y, xc.y, fmaf(wv.x, xc.x, a0))));
    a1 = fmaf(wv.w, xn.x, fmaf(wv.z, xc.w, fmaf(wv.y, xc.z, fmaf(wv.x, xc.y, a1))));
    a2 = fmaf(wv.w, xn.y, fmaf(wv.z, xn.x, fmaf(wv.y, xc.w, fmaf(wv.x, xc.z, a2))));
    a3 = fmaf(wv.w, xn.z, fmaf(wv.z, xn.y, fmaf(wv.y, xn.x, fmaf(wv.x, xc.w, a3))));
    xc = xn;
  }
  float wk = wrow[128];
  a0 = fmaf(wk, xc.x, a0); a1 = fmaf(wk, xc.y, a1);
  a2 = fmaf(wk, xc.z, a2); a3 = fmaf(wk, xc.w, a3);
}

struct SeqArgs {
  const float* input;
  const float* nv1_0; const float* nv2_0; const float* nv1_1; const float* nv2_1;
  const float* w_start0; const float* b_start0; const float* w_mlp0; const float* b_mlp0;
  const float* w_end0;   const float* b_end0;   const float* w_lin0; const float* b_lin0;
  const float* gamma0;   const float* beta0;
  const float* w_start1; const float* b_start1; const float* w_mlp1; const float* b_mlp1;
  const float* w_end1;   const float* b_end1;   const float* w_lin1; const float* b_lin1;
  const float* gamma1;   const float* beta1;
  u64*   HCOL2;  // ws ring [16][192][192] of {f32 val, u32 tag}
  int*   prog;   // ws [192*32] ints, stride 32: consumer progress (backpressure)
  float* out_all; float* out_hrow; float* out_hcol;
};

__global__ __launch_bounds__(NT, 2) void seq_kernel(SeqArgs A) {
  const int n = blockIdx.x, w = n >> 3, b = n & 7, tid = threadIdx.x;
  const int pred = (n + 184) % 192;   // n-8 mod 192
  const int succ = (n + 8) % 192;

  __shared__ __align__(16) float sCIN[384];     // h_row(0..191) | h_col(192..383)
  __shared__ __align__(16) float sXB[2][384];   // x double buffer
  __shared__ __align__(16) float sWSf[64 * 132];// conv weights fp32 (bf16-rounded)
  __shared__ __align__(16) float sAT[4096];     // aT[w*64+v]
  __shared__ __align__(16) float sH[2][1024];   // h0 / h1 rows [c*64+v]
  __shared__ __align__(16) float sPreP[2048];   // x-channel partials (p-1)[c][v]
  __shared__ __align__(16) float sAbuf[4928];
  float* const sPart = sAbuf;          // [0..1023] h_row-channel partials
  float* const sG    = sAbuf;          // [0..2047]
  float* const sH2c  = sAbuf + 2048;   // [2048..3071] h2 rows (dead after G)
  float* const sE    = sAbuf + 2048;   // [2048..2431] (overwrites dead h2)
  float* const sY    = sAbuf;          // [0..1151]   (overwrites dead sG)
  float* const smWE  = sAbuf + 3072;   // 192
  float* const smBE  = sAbuf + 3264;   // 6
  float* const smWM  = sAbuf + 3328;   // 32*50 (stride 50: bank-conflict-free)

  for (int layer = 0; layer < 2; ++layer) {
    const int in_dim = 3 + layer;
    const int P = in_dim - 1;  // pre channels: h_row + (P-1) x-channels
    const float* nv1    = layer ? A.nv1_1    : A.nv1_0;
    const float* nv2    = layer ? A.nv2_1    : A.nv2_0;
    const float* wstart = layer ? A.w_start1 : A.w_start0;
    const float* bs     = layer ? A.b_start1 : A.b_start0;
    const float* wm     = layer ? A.w_mlp1   : A.w_mlp0;
    const float* bm     = layer ? A.b_mlp1   : A.b_mlp0;
    const float* we     = layer ? A.w_end1   : A.w_end0;
    const float* be     = layer ? A.b_end1   : A.b_end0;
    const float* wl     = layer ? A.w_lin1   : A.w_lin0;
    const float* bl     = layer ? A.b_lin1   : A.b_lin0;
    const float* gm     = layer ? A.gamma1   : A.gamma0;
    const float* bt     = layer ? A.beta1    : A.beta0;

    // ---- layer init: adjacency, weights (fp32, bf16-rounded), state zero ----
    // scores use sAbuf[0..4095]
    for (int idx = tid; idx < 4096; idx += NT) {
      int v = idx >> 6, ww = idx & 63;
      float s = 0.f;
      for (int j = 0; j < 40; ++j) s = fmaf(nv1[v*40 + j], nv2[j*64 + ww], s);
      sAbuf[idx] = fmaxf(s, 0.f);
    }
    __syncthreads();
    if (tid < 64) {
      const int v = tid;
      float m = -1e30f;
      for (int ww = 0; ww < 64; ++ww) m = fmaxf(m, sAbuf[v*64 + ww]);
      float s = 0.f;
      for (int ww = 0; ww < 64; ++ww) { float e = expf(sAbuf[v*64 + ww] - m); sAbuf[v*64 + ww] = e; s += e; }
      float inv = 1.f / s, rs = 1.f;
      for (int ww = 0; ww < 64; ++ww) rs += sAbuf[v*64 + ww] * inv;
      float irs = 1.f / rs;
      for (int ww = 0; ww < 64; ++ww) {
        float a = sAbuf[v*64 + ww] * inv + ((ww == v) ? 1.f : 0.f);
        sAT[ww*64 + v] = a * irs;
      }
    }
    __syncthreads();  // sAT ready; scores region dead
    for (int idx = tid; idx < 16*in_dim*132; idx += NT) {
      int row = idx / 132, k = idx - row*132;
      sWSf[idx] = (k < 129) ? frombf(tobf(wstart[((row & 15)*in_dim + (row >> 4))*129 + k])) : 0.f;
    }
    for (int idx = tid; idx < 1536; idx += NT) { int o = idx/48, c = idx - o*48; smWM[o*50 + c] = wm[idx]; }
    for (int idx = tid; idx < 192; idx += NT) smWE[idx] = we[idx];
    if (tid < 6) smBE[tid] = be[tid];
    for (int d = tid; d < 384; d += NT) sCIN[d] = 0.f;

    const int v_p = tid & 63;
    const int o0  = tid >> 6;         // wave id, 0..7
    const float bmv0 = bm[o0], bmv1 = bm[o0 + 8], bmv2 = bm[o0 + 16], bmv3 = bm[o0 + 24];
    float blv = 0.f, gmv = 1.f, btv = 0.f;
    if (tid < 384) blv = bl[(tid >= 192) ? tid - 192 : tid];
    if (tid < 192) { gmv = gm[tid]; btv = bt[tid]; }
    float bs_r[2];
    bs_r[0] = bs[tid >> 6];
    bs_r[1] = bs[(tid >> 6) + 8];
    __syncthreads();

    // ---- prologue: stage x(0)->sXB[0]; conv all P channels; assemble h0pre ----
    {
      if (layer == 0) {
        int o = 0 - w;
        for (int d = tid; d < 192; d += NT)
          sXB[0][d] = (o >= 0 && o < 48) ? A.input[(((size_t)(b*24 + w)*48 + o)*192) + d] : 0.f;
      } else {
        for (int d = tid; d < 384; d += NT)
          sXB[0][d] = A.out_all[((size_t)n*71 + 0)*384 + d];
      }
      bar_light();
      const int nslots = P << 8;
      for (int s = tid; s < nslots; s += NT) {
        const int cidx = s >> 4;
        const int p = cidx >> 4, c = cidx & 15;
        const int vg = s & 15;
        const int ich = (p == 0) ? 0 : (p + 1);
        const float* xin = ((p == 0) ? &sCIN[0] : &sXB[0][(p-1)*192]) + vg*4;
        float a0 = 0.f, a1 = 0.f, a2 = 0.f, a3 = 0.f;
        conv4(&sWSf[(ich*16 + c)*132], xin, a0, a1, a2, a3);
        float* dst = (p == 0) ? &sPart[c*64 + vg*4] : &sPreP[(p-1)*1024 + c*64 + vg*4];
        *(float4*)dst = make_float4(a0, a1, a2, a3);
      }
      bar_light();
      {
        const int c0 = tid >> 6, v = tid & 63;
        float sum0 = bs_r[0], sum1 = bs_r[1];
        sum0 += sPart[c0*64 + v];
        sum1 += sPart[(c0+8)*64 + v];
        for (int p = 1; p < P; ++p) {
          sum0 += sPreP[(p-1)*1024 + c0*64 + v];
          sum1 += sPreP[(p-1)*1024 + (c0+8)*64 + v];
        }
        sH[0][ c0     *64 + v] = sum0;
        sH[0][(c0 + 8)*64 + v] = sum1;
      }
      bar_light();
    }

    for (int t = 0; t < 71; ++t) {
      const int S = layer*71 + t;

      // ---- step top: x(t+1) reg-prefetch (crew 256-447) + poll (crew <192) ----
      float xpa = 0.f, xpb = 0.f;
      if (t < 70 && tid >= 256 && tid < 448) {
        const int d = tid - 256;
        if (layer == 0) {
          int o = (t + 1) - w;
          if (o >= 0 && o < 48)
            xpa = A.input[(((size_t)(b*24 + w)*48 + o)*192) + d];
        } else {
          const float* xr = A.out_all + ((size_t)n*71 + (t+1))*384;
          xpa = xr[d];
          xpb = xr[192 + d];
        }
      }
      if (t > 0) {
        if (tid < 192) {
          const u64* src = &A.HCOL2[((size_t)((S-1) & 15)*192 + pred)*192 + tid];
          u64 v = __hip_atomic_load(src, __ATOMIC_RELAXED, __HIP_MEMORY_SCOPE_AGENT);
          while ((unsigned)(v >> 32) != (unsigned)S) {
            __builtin_amdgcn_s_sleep(1);
            v = __hip_atomic_load(src, __ATOMIC_RELAXED, __HIP_MEMORY_SCOPE_AGENT);
          }
          __builtin_amdgcn_sched_barrier(0);
          asm volatile("" ::: "memory");
          sCIN[192 + tid] = __uint_as_float((unsigned)v);
        } else if (tid == 448 && S >= 16) {
          while (__hip_atomic_load(&A.prog[succ*32], __ATOMIC_RELAXED, __HIP_MEMORY_SCOPE_AGENT) < S - 15)
            __builtin_amdgcn_s_sleep(2);
        }
        bar_light();  // Bp
        if (tid == 0)
          __hip_atomic_store(&A.prog[n*32], S, __ATOMIC_RELAXED, __HIP_MEMORY_SCOPE_AGENT);
      } else if (S >= 16) {  // t==0, layer 1: still must respect ring reuse
        if (tid == 448) {
          while (__hip_atomic_load(&A.prog[succ*32], __ATOMIC_RELAXED, __HIP_MEMORY_SCOPE_AGENT) < S - 15)
            __builtin_amdgcn_s_sleep(2);
        }
      }

      // ---- phase A (wave-local): h_col conv -> prop1 -> prop2 ----
      {
        const int c = tid >> 5, vg2 = tid & 31;
        const int vbase = c*64 + vg2*2;
        const float* xin = &sCIN[192 + vg2*2];
        const float* wrow = &sWSf[(16 + c)*132];
        float a0 = sH[0][vbase], a1 = sH[0][vbase + 1];
        float2 xc = *(const float2*)xin;
        for (int k2 = 0; k2 < 128; k2 += 2) {
          float2 wv = *(const float2*)(wrow + k2);
          float2 xn = *(const float2*)(xin + k2 + 2);
          a0 = fmaf(wv.y, xc.y, fmaf(wv.x, xc.x, a0));
          a1 = fmaf(wv.y, xn.x, fmaf(wv.x, xc.y, a1));
          xc = xn;
        }
        float wk = wrow[128];
        a0 = fmaf(wk, xc.x, a0); a1 = fmaf(wk, xc.y, a1);
        sH[0][vbase] = a0; sH[0][vbase + 1] = a1;
      }
      lds_fence();
      {
        const int c0 = o0 * 2;   // this wave's 2 rows
        float pa0 = 0.f, pa1 = 0.f;
        for (int w4 = 0; w4 < 64; w4 += 4) {
          float a0v = sAT[(w4+0)*64 + v_p];
          float a1v = sAT[(w4+1)*64 + v_p];
          float a2v = sAT[(w4+2)*64 + v_p];
          float a3v = sAT[(w4+3)*64 + v_p];
          float4 h0v = *(const float4*)&sH[0][ c0      *64 + w4];
          float4 h1v = *(const float4*)&sH[0][(c0 + 1 )*64 + w4];
          pa0 = fmaf(h0v.x, a0v, pa0); pa0 = fmaf(h0v.y, a1v, pa0);
          pa0 = fmaf(h0v.z, a2v, pa0); pa0 = fmaf(h0v.w, a3v, pa0);
          pa1 = fmaf(h1v.x, a0v, pa1); pa1 = fmaf(h1v.y, a1v, pa1);
          pa1 = fmaf(h1v.z, a2v, pa1); pa1 = fmaf(h1v.w, a3v, pa1);
        }
        float h0a = sH[0][ c0      *64 + v_p];
        float h0b = sH[0][(c0 + 1 )*64 + v_p];
        sH[1][ c0      *64 + v_p] = fmaf(0.95f, pa0, 0.05f * h0a);
        sH[1][(c0 + 1 )*64 + v_p] = fmaf(0.95f, pa1, 0.05f * h0b);
        lds_fence();
        float pb0 = 0.f, pb1 = 0.f;
        for (int w4 = 0; w4 < 64; w4 += 4) {
          float a0v = sAT[(w4+0)*64 + v_p];
          float a1v = sAT[(w4+1)*64 + v_p];
          float a2v = sAT[(w4+2)*64 + v_p];
          float a3v = sAT[(w4+3)*64 + v_p];
          float4 h0v = *(const float4*)&sH[1][ c0      *64 + w4];
          float4 h1v = *(const float4*)&sH[1][(c0 + 1 )*64 + w4];
          pb0 = fmaf(h0v.x, a0v, pb0); pb0 = fmaf(h0v.y, a1v, pb0);
          pb0 = fmaf(h0v.z, a2v, pb0); pb0 = fmaf(h0v.w, a3v, pb0);
          pb1 = fmaf(h1v.x, a0v, pb1); pb1 = fmaf(h1v.y, a1v, pb1);
          pb1 = fmaf(h1v.z, a2v, pb1); pb1 = fmaf(h1v.w, a3v, pb1);
        }
        sH2c[ c0      *64 + v_p] = fmaf(0.95f, pb0, 0.05f * h0a);
        sH2c[(c0 + 1 )*64 + v_p] = fmaf(0.95f, pb1, 0.05f * h0b);
      }
      bar_light();  // B3: h0/h1/h2 all ready

      // (g) G = bm + wm0 h0 + wm1 h1 + wm2 h2; exact GELU -> sG
      {
        float g0 = bmv0, g1 = bmv1, g2 = bmv2, g3 = bmv3;
#pragma unroll
        for (int c = 0; c < 16; ++c) {
          float h0v = sH[0][c*64 + v_p];
          float h1v = sH[1][c*64 + v_p];
          float h2v = sH2c[c*64 + v_p];
          g0 = fmaf(smWM[(o0     )*50 + c], h0v, fmaf(smWM[(o0     )*50 + 16 + c], h1v, fmaf(smWM[(o0     )*50 + 32 + c], h2v, g0)));
          g1 = fmaf(smWM[(o0 +  8)*50 + c], h0v, fmaf(smWM[(o0 +  8)*50 + 16 + c], h1v, fmaf(smWM[(o0 +  8)*50 + 32 + c], h2v, g1)));
          g2 = fmaf(smWM[(o0 + 16)*50 + c], h0v, fmaf(smWM[(o0 + 16)*50 + 16 + c], h1v, fmaf(smWM[(o0 + 16)*50 + 32 + c], h2v, g2)));
          g3 = fmaf(smWM[(o0 + 24)*50 + c], h0v, fmaf(smWM[(o0 + 24)*50 + 16 + c], h1v, fmaf(smWM[(o0 + 24)*50 + 32 + c], h2v, g3)));
        }
        g0 = 0.5f * g0 * (1.f + erff(g0 * 0.70710678118654752f));
        g1 = 0.5f * g1 * (1.f + erff(g1 * 0.70710678118654752f));
        g2 = 0.5f * g2 * (1.f + erff(g2 * 0.70710678118654752f));
        g3 = 0.5f * g3 * (1.f + erff(g3 * 0.70710678118654752f));
        sG[(o0     )*64 + v_p] = g0;
        sG[(o0 +  8)*64 + v_p] = g1;
        sG[(o0 + 16)*64 + v_p] = g2;
        sG[(o0 + 24)*64 + v_p] = g3;
      }
      bar_light();  // B4 (h2 region now dead -> sE may overwrite)

      // (h) E = be + we @ G
      for (int idx = tid; idx < 384; idx += NT) {
        int o2 = idx >> 6, v = idx & 63;
        float acc = smBE[o2];
        for (int c = 0; c < 32; ++c) acc = fmaf(smWE[o2*32 + c], sG[c*64 + v], acc);
        sE[idx] = acc;
      }
      bar_light();  // B5

      // (i) Y = bl + E @ wl^T : 384 threads, 3 rows each
      if (tid < 384) {
        const int d  = (tid >= 192) ? tid - 192 : tid;
        const int r0 = (tid >= 192) ? 3 : 0;
        const float4* wrow = (const float4*)(wl + d*64);
        float y0 = blv, y1 = blv, y2 = blv;
        for (int q = 0; q < 16; ++q) {
          float4 wv = wrow[q];
          float4 e0 = *(const float4*)&sE[(r0+0)*64 + q*4];
          float4 e1 = *(const float4*)&sE[(r0+1)*64 + q*4];
          float4 e2 = *(const float4*)&sE[(r0+2)*64 + q*4];
          y0 = fmaf(e0.x,wv.x, fmaf(e0.y,wv.y, fmaf(e0.z,wv.z, fmaf(e0.w,wv.w, y0))));
          y1 = fmaf(e1.x,wv.x, fmaf(e1.y,wv.y, fmaf(e1.z,wv.z, fmaf(e1.w,wv.w, y1))));
          y2 = fmaf(e2.x,wv.x, fmaf(e2.y,wv.y, fmaf(e2.z,wv.z, fmaf(e2.w,wv.w, y2))));
        }
        sY[(r0+0)*192 + d] = y0;
        sY[(r0+1)*192 + d] = y1;
        sY[(r0+2)*192 + d] = y2;
      }
      bar_light();  // B6

      // (j1) LN stats -> sH[1][0..13]
      if (tid < 192) {
        const int r = tid >> 5, l32 = tid & 31;
        float sm = 0.f, sq = 0.f;
#pragma unroll
        for (int m = 0; m < 6; ++m) {
          float v = sY[r*192 + l32 + 32*m];
          sm += v; sq = fmaf(v, v, sq);
        }
#pragma unroll
        for (int off = 16; off >= 1; off >>= 1) {
          sm += __shfl_xor(sm, off);
          sq += __shfl_xor(sq, off);
        }
        if (l32 == 0) {
          float mu = sm * (1.f/192.f);
          float var = sq * (1.f/192.f) - mu*mu;
          sH[1][r] = mu;
          sH[1][8 + r] = rsqrtf(fmaxf(var, 0.f) + 1e-5f);
        }
      }
      bar_light();  // B7

      float hcn = 0.f;
      // (k1) col gates -> hcn -> tagged 8B store  ∥  x-publish (crew 256-447)
      if (tid < 192) {
        const int d = tid;
        float y2 = fmaf((sY[2*192+d] - sH[1][2]) * sH[1][10], gmv, btv);
        float y3 = fmaf((sY[3*192+d] - sH[1][3]) * sH[1][11], gmv, btv);
        float y5 = fmaf((sY[5*192+d] - sH[1][5]) * sH[1][13], gmv, btv);
        float ugc = sigf(y2), ogc = sigf(y3), igc = tanh_fast(y5);
        float hc = sCIN[192 + d];
        hcn = tanh_fast(fmaf(ugc, igc, (1.f - ugc)*hc)) * ogc;
        u64 pk = ((u64)(unsigned)(S + 1) << 32) | (u64)__float_as_uint(hcn);
        __hip_atomic_store(&A.HCOL2[((size_t)(S & 15)*192 + n)*192 + d], pk,
                           __ATOMIC_RELAXED, __HIP_MEMORY_SCOPE_AGENT);
      } else if (t < 70 && tid >= 256 && tid < 448) {
        const int d = tid - 256;
        float* xbn = &sXB[(t+1) & 1][0];
        xbn[d] = xpa;
        if (layer == 1) xbn[192 + d] = xpb;
      }
      bar_light();  // B8: x(t+1) visible to conv crew

      // (k2) row gates + outputs (crew <192)  ∥  x-channel convs (crew 192-447)
      if (tid < 192) {
        const int d = tid;
        float y0 = fmaf((sY[0*192+d] - sH[1][0]) * sH[1][8],  gmv, btv);
        float y1 = fmaf((sY[1*192+d] - sH[1][1]) * sH[1][9],  gmv, btv);
        float y4 = fmaf((sY[4*192+d] - sH[1][4]) * sH[1][12], gmv, btv);
        float ugr = sigf(y0), ogr = sigf(y1), igr = tanh_fast(y4);
        float hr = sCIN[d];
        float hrn = tanh_fast(fmaf(ugr, igr, (1.f - ugr)*hr)) * ogr;
        sCIN[d] = hrn;
        float* oa = A.out_all + ((size_t)n*71 + t)*384;
        if (layer == 0) { oa[d] = hrn; oa[192 + d] = hcn; }
        else {
          const float* xbt = &sXB[t & 1][0];
          oa[d] = hrn + xbt[d]; oa[192 + d] = hcn + xbt[192 + d];
        }
        if (t == 47 + w)
          A.out_hrow[(((size_t)b*2 + layer)*24 + w)*192 + d] = hrn;
        if (w == 23 && t >= 23)
          A.out_hcol[(((size_t)b*2 + layer)*48 + (t - 23))*192 + d] = hcn;
      } else if (t < 70 && tid >= 192 && tid < 448) {
        // x-channel pre-convs for step t+1 (p = 1..P-1), hidden under k2
        const int sl = tid - 192;                   // 0..255
        const int nx = (P - 1) << 8;                // 256 or 512 slots
        const float* xbn = &sXB[(t+1) & 1][0];
        for (int s = sl; s < nx; s += 256) {
          const int p = 1 + (s >> 8);
          const int c = (s >> 4) & 15, vg = s & 15;
          const int ich = p + 1;
          float a0 = 0.f, a1 = 0.f, a2 = 0.f, a3 = 0.f;
          conv4(&sWSf[(ich*16 + c)*132], &xbn[(p-1)*192 + vg*4], a0, a1, a2, a3);
          *(float4*)&sPreP[(p-1)*1024 + c*64 + vg*4] = make_float4(a0, a1, a2, a3);
        }
      }
      bar_light();  // B9: h_row updated; x-partials ready

      // ---- serial tail (t<70): h_row conv + assemble h0pre(t+1) ----
      if (t < 70) {
        if (tid < 256) {
          const int c = tid >> 4, vg = tid & 15;
          float a0 = 0.f, a1 = 0.f, a2 = 0.f, a3 = 0.f;
          conv4(&sWSf[c*132], &sCIN[vg*4], a0, a1, a2, a3);
          *(float4*)&sPart[c*64 + vg*4] = make_float4(a0, a1, a2, a3);
        }
        bar_light();  // B10
        {
          const int c0 = tid >> 6, v = tid & 63;
          float sum0 = bs_r[0], sum1 = bs_r[1];
          sum0 += sPart[c0*64 + v];
          sum1 += sPart[(c0+8)*64 + v];
          for (int p = 1; p < P; ++p) {
            sum0 += sPreP[(p-1)*1024 + c0*64 + v];
            sum1 += sPreP[(p-1)*1024 + (c0+8)*64 + v];
          }
          sH[0][ c0     *64 + v] = sum0;
          sH[0][(c0 + 8)*64 + v] = sum1;
        }
        bar_light();  // B11
      }
    } // t
    __syncthreads();  // drain out_all before next layer reads it
  } // layer
}

extern "C" void kernel_launch(void* const* d_in, const int* in_sizes, int n_in,
                              void* d_out, int out_size, void* d_ws, size_t ws_size,
                              hipStream_t stream) {
  (void)in_sizes; (void)n_in; (void)out_size; (void)ws_size;
  char* ws = (char*)d_ws;
  int* prog  = (int*)ws;                   // 24,576 B (192 x 128B)
  u64* HCOL2 = (u64*)(ws + 24576);         // 16*192*192*8 = 4,718,592 B

  (void)hipMemsetAsync(ws, 0, 24576 + 4718592, stream);  // zero prog + tags

  SeqArgs A;
  A.input    = (const float*)d_in[0];
  A.nv1_0    = (const float*)d_in[1];  A.nv2_0 = (const float*)d_in[2];
  A.w_start0 = (const float*)d_in[3];  A.b_start0 = (const float*)d_in[4];
  A.w_mlp0   = (const float*)d_in[5];  A.b_mlp0   = (const float*)d_in[6];
  A.w_end0   = (const float*)d_in[7];  A.b_end0   = (const float*)d_in[8];
  A.w_lin0   = (const float*)d_in[9];  A.b_lin0   = (const float*)d_in[10];
  A.gamma0   = (const float*)d_in[11]; A.beta0    = (const float*)d_in[12];
  A.nv1_1    = (const float*)d_in[13]; A.nv2_1 = (const float*)d_in[14];
  A.w_start1 = (const float*)d_in[15]; A.b_start1 = (const float*)d_in[16];
  A.w_mlp1   = (const float*)d_in[17]; A.b_mlp1   = (const float*)d_in[18];
  A.w_end1   = (const float*)d_in[19]; A.b_end1   = (const float*)d_in[20];
  A.w_lin1   = (const float*)d_in[21]; A.b_lin1   = (const float*)d_in[22];
  A.gamma1   = (const float*)d_in[23]; A.beta1    = (const float*)d_in[24];
  A.HCOL2 = HCOL2; A.prog = prog;
  A.out_all  = (float*)d_out;
  A.out_hrow = (float*)d_out + 5234688;
  A.out_hcol = (float*)d_out + 5308416;

  seq_kernel<<<192, NT, 0, stream>>>(A);
}